// Round 3
// baseline (275.865 us; speedup 1.0000x reference)
//
#include <hip/hip_runtime.h>

#define NBLOCKS 2048
#define NTHREADS 256
#define UNROLL 8   // 8 float4 = 128 B per thread per stream per chunk

__global__ __launch_bounds__(NTHREADS, 4) void l1_fused_kernel(
    const float4* __restrict__ a, const float4* __restrict__ b,
    const float* __restrict__ af, const float* __restrict__ bf,
    float* __restrict__ out, long n4, long n_total, float inv_n) {
    const int tid = threadIdx.x;
    const long chunk = (long)NTHREADS * UNROLL;   // 2048 float4 (32 KB) per block-chunk
    const long nchunks = n4 / chunk;

    float acc[UNROLL];
    #pragma unroll
    for (int j = 0; j < UNROLL; ++j) acc[j] = 0.f;

    for (long c = blockIdx.x; c < nchunks; c += NBLOCKS) {
        const long base = c * chunk + tid;
        float4 xs[UNROLL], ys[UNROLL];
        // 16 independent dwordx4 loads issued back-to-back before any use:
        #pragma unroll
        for (int j = 0; j < UNROLL; ++j) xs[j] = a[base + j * NTHREADS];
        #pragma unroll
        for (int j = 0; j < UNROLL; ++j) ys[j] = b[base + j * NTHREADS];
        #pragma unroll
        for (int j = 0; j < UNROLL; ++j)
            acc[j] += fabsf(xs[j].x - ys[j].x) + fabsf(xs[j].y - ys[j].y)
                    + fabsf(xs[j].z - ys[j].z) + fabsf(xs[j].w - ys[j].w);
    }

    // remainder float4s not covered by full chunks (none for this shape)
    float racc = 0.f;
    const long gid = (long)blockIdx.x * NTHREADS + tid;
    const long tthreads = (long)NBLOCKS * NTHREADS;
    for (long i = nchunks * chunk + gid; i < n4; i += tthreads) {
        float4 x = a[i], y = b[i];
        racc += fabsf(x.x - y.x) + fabsf(x.y - y.y)
              + fabsf(x.z - y.z) + fabsf(x.w - y.w);
    }
    // scalar tail for n % 4 (none for this shape)
    for (long e = n4 * 4 + gid; e < n_total; e += tthreads)
        racc += fabsf(af[e] - bf[e]);

    // pairwise combine
    float acc_total = ((acc[0] + acc[1]) + (acc[2] + acc[3]))
                    + ((acc[4] + acc[5]) + (acc[6] + acc[7])) + racc;

    // wave-64 reduction
    #pragma unroll
    for (int off = 32; off > 0; off >>= 1)
        acc_total += __shfl_down(acc_total, off, 64);

    __shared__ float smem[NTHREADS / 64];
    int wave = tid >> 6;
    int lane = tid & 63;
    if (lane == 0) smem[wave] = acc_total;
    __syncthreads();
    if (tid == 0) {
        float s = 0.f;
        #pragma unroll
        for (int w = 0; w < NTHREADS / 64; ++w) s += smem[w];
        atomicAdd(out, s * inv_n);  // ~2048 adds to one address, device-scope
    }
}

extern "C" void kernel_launch(void* const* d_in, const int* in_sizes, int n_in,
                              void* d_out, int out_size, void* d_ws, size_t ws_size,
                              hipStream_t stream) {
    const float* yhat = (const float*)d_in[0];
    const float* y    = (const float*)d_in[1];
    float* out = (float*)d_out;

    long n = (long)in_sizes[0];
    long n4 = n / 4;
    float inv_n = 1.0f / (float)n;

    // d_out is poisoned 0xAA before every launch — zero the accumulator first.
    hipMemsetAsync(out, 0, sizeof(float), stream);
    l1_fused_kernel<<<NBLOCKS, NTHREADS, 0, stream>>>(
        (const float4*)yhat, (const float4*)y, yhat, y, out, n4, n, inv_n);
}

// Round 4
// 272.558 us; speedup vs baseline: 1.0121x; 1.0121x over previous
//
#include <hip/hip_runtime.h>

#define NBLOCKS 2048
#define NTHREADS 256
#define UNROLL 8   // 8 float4 per stream = 16 x dwordx4 = 256 B/lane in flight

#if defined(__has_builtin)
#  if __has_builtin(__builtin_amdgcn_sched_barrier)
#    define SCHED_FENCE() __builtin_amdgcn_sched_barrier(0)
#  endif
#endif
#ifndef SCHED_FENCE
#  define SCHED_FENCE()
#endif

__global__ __launch_bounds__(NTHREADS, 4) void l1_fused_kernel(
    const float4* __restrict__ a, const float4* __restrict__ b,
    const float* __restrict__ af, const float* __restrict__ bf,
    float* __restrict__ out, long n4, long n_total, float inv_n) {
    const int tid = threadIdx.x;
    const long chunk = (long)NTHREADS * UNROLL;   // 2048 float4 (32 KB) per block-chunk
    const long nchunks = n4 / chunk;

    float acc[UNROLL];
    #pragma unroll
    for (int j = 0; j < UNROLL; ++j) acc[j] = 0.f;

    for (long c = blockIdx.x; c < nchunks; c += NBLOCKS) {
        const long base = c * chunk + tid;
        float4 xs[UNROLL], ys[UNROLL];
        #pragma unroll
        for (int j = 0; j < UNROLL; ++j) xs[j] = a[base + j * NTHREADS];
        #pragma unroll
        for (int j = 0; j < UNROLL; ++j) ys[j] = b[base + j * NTHREADS];
        // Hard fence: scheduler may not sink the 16 loads past this point,
        // so all of them are issued before the first use (vmcnt pipelining).
        SCHED_FENCE();
        #pragma unroll
        for (int j = 0; j < UNROLL; ++j)
            acc[j] += fabsf(xs[j].x - ys[j].x) + fabsf(xs[j].y - ys[j].y)
                    + fabsf(xs[j].z - ys[j].z) + fabsf(xs[j].w - ys[j].w);
    }

    // remainder float4s not covered by full chunks (none for this shape)
    float racc = 0.f;
    const long gid = (long)blockIdx.x * NTHREADS + tid;
    const long tthreads = (long)NBLOCKS * NTHREADS;
    for (long i = nchunks * chunk + gid; i < n4; i += tthreads) {
        float4 x = a[i], y = b[i];
        racc += fabsf(x.x - y.x) + fabsf(x.y - y.y)
              + fabsf(x.z - y.z) + fabsf(x.w - y.w);
    }
    // scalar tail for n % 4 (none for this shape)
    for (long e = n4 * 4 + gid; e < n_total; e += tthreads)
        racc += fabsf(af[e] - bf[e]);

    float acc_total = ((acc[0] + acc[1]) + (acc[2] + acc[3]))
                    + ((acc[4] + acc[5]) + (acc[6] + acc[7])) + racc;

    #pragma unroll
    for (int off = 32; off > 0; off >>= 1)
        acc_total += __shfl_down(acc_total, off, 64);

    __shared__ float smem[NTHREADS / 64];
    int wave = tid >> 6;
    int lane = tid & 63;
    if (lane == 0) smem[wave] = acc_total;
    __syncthreads();
    if (tid == 0) {
        float s = 0.f;
        #pragma unroll
        for (int w = 0; w < NTHREADS / 64; ++w) s += smem[w];
        atomicAdd(out, s * inv_n);  // ~2048 adds to one address, device-scope
    }
}

extern "C" void kernel_launch(void* const* d_in, const int* in_sizes, int n_in,
                              void* d_out, int out_size, void* d_ws, size_t ws_size,
                              hipStream_t stream) {
    const float* yhat = (const float*)d_in[0];
    const float* y    = (const float*)d_in[1];
    float* out = (float*)d_out;

    long n = (long)in_sizes[0];
    long n4 = n / 4;
    float inv_n = 1.0f / (float)n;

    // d_out is poisoned 0xAA before every launch — zero the accumulator first.
    hipMemsetAsync(out, 0, sizeof(float), stream);
    l1_fused_kernel<<<NBLOCKS, NTHREADS, 0, stream>>>(
        (const float4*)yhat, (const float4*)y, yhat, y, out, n4, n, inv_n);
}

// Round 6
// 256.379 us; speedup vs baseline: 1.0760x; 1.0631x over previous
//
#include <hip/hip_runtime.h>

#define NBLOCKS 2048
#define NTHREADS 256
#define UNROLL 8   // 8 vec4 per stream per chunk iteration

typedef float vfloat4 __attribute__((ext_vector_type(4)));

#if defined(__has_builtin)
#  if __has_builtin(__builtin_amdgcn_sched_barrier)
#    define SCHED_FENCE() __builtin_amdgcn_sched_barrier(0)
#  endif
#endif
#ifndef SCHED_FENCE
#  define SCHED_FENCE()
#endif

__global__ __launch_bounds__(NTHREADS, 4) void l1_fused_kernel(
    const vfloat4* __restrict__ a, const vfloat4* __restrict__ b,
    const float* __restrict__ af, const float* __restrict__ bf,
    float* __restrict__ out, long n4, long n_total, float inv_n) {
    const int tid = threadIdx.x;
    const long chunk = (long)NTHREADS * UNROLL;   // 2048 vec4 (32 KB) per block-chunk
    const long nchunks = n4 / chunk;

    float acc[UNROLL];
    #pragma unroll
    for (int j = 0; j < UNROLL; ++j) acc[j] = 0.f;

    for (long c = blockIdx.x; c < nchunks; c += NBLOCKS) {
        const long base = c * chunk + tid;
        vfloat4 xs[UNROLL], ys[UNROLL];
        // Nontemporal: nt policy bypasses L1 allocation (deeper L2 queues),
        // avoids thrashing the exactly-256MiB L3 working set.
        #pragma unroll
        for (int j = 0; j < UNROLL; ++j)
            xs[j] = __builtin_nontemporal_load(&a[base + j * NTHREADS]);
        #pragma unroll
        for (int j = 0; j < UNROLL; ++j)
            ys[j] = __builtin_nontemporal_load(&b[base + j * NTHREADS]);
        SCHED_FENCE();
        #pragma unroll
        for (int j = 0; j < UNROLL; ++j) {
            vfloat4 d = xs[j] - ys[j];
            acc[j] += fabsf(d.x) + fabsf(d.y) + fabsf(d.z) + fabsf(d.w);
        }
    }

    // remainder vec4s not covered by full chunks (none for this shape)
    float racc = 0.f;
    const long gid = (long)blockIdx.x * NTHREADS + tid;
    const long tthreads = (long)NBLOCKS * NTHREADS;
    for (long i = nchunks * chunk + gid; i < n4; i += tthreads) {
        vfloat4 x = a[i], y = b[i];
        racc += fabsf(x.x - y.x) + fabsf(x.y - y.y)
              + fabsf(x.z - y.z) + fabsf(x.w - y.w);
    }
    // scalar tail for n % 4 (none for this shape)
    for (long e = n4 * 4 + gid; e < n_total; e += tthreads)
        racc += fabsf(af[e] - bf[e]);

    float acc_total = ((acc[0] + acc[1]) + (acc[2] + acc[3]))
                    + ((acc[4] + acc[5]) + (acc[6] + acc[7])) + racc;

    #pragma unroll
    for (int off = 32; off > 0; off >>= 1)
        acc_total += __shfl_down(acc_total, off, 64);

    __shared__ float smem[NTHREADS / 64];
    int wave = tid >> 6;
    int lane = tid & 63;
    if (lane == 0) smem[wave] = acc_total;
    __syncthreads();
    if (tid == 0) {
        float s = 0.f;
        #pragma unroll
        for (int w = 0; w < NTHREADS / 64; ++w) s += smem[w];
        atomicAdd(out, s * inv_n);  // ~2048 adds to one address, device-scope
    }
}

extern "C" void kernel_launch(void* const* d_in, const int* in_sizes, int n_in,
                              void* d_out, int out_size, void* d_ws, size_t ws_size,
                              hipStream_t stream) {
    const float* yhat = (const float*)d_in[0];
    const float* y    = (const float*)d_in[1];
    float* out = (float*)d_out;

    long n = (long)in_sizes[0];
    long n4 = n / 4;
    float inv_n = 1.0f / (float)n;

    // d_out is poisoned 0xAA before every launch — zero the accumulator first.
    (void)hipMemsetAsync(out, 0, sizeof(float), stream);
    l1_fused_kernel<<<NBLOCKS, NTHREADS, 0, stream>>>(
        (const vfloat4*)yhat, (const vfloat4*)y, yhat, y, out, n4, n, inv_n);
}